// Round 1
// baseline (891.237 us; speedup 1.0000x reference)
//
#include <hip/hip_runtime.h>
#include <cstddef>

#define NB     128
#define NIN    1152
#define NOUT   10
#define DOUT   16
#define DIN    8
#define IBLK   8
#define NCHUNK (NIN / IBLK)      // 144
#define OD     (NOUT * DOUT)     // 160

__device__ __forceinline__ float clip10(float x) {
    return fminf(10.0f, fmaxf(-10.0f, x));
}

// 256 threads: lane = bl*4 + isub (within wave: 16 b x 4 isub)
//   bl   = tid >> 2  (0..63)  -> b = bgroup*64 + bl
//   isub = tid & 3            -> owns d in [isub*4, isub*4+4) for every o
// grid = NCHUNK*2 : chunk = bx>>1, bgroup = bx&1
template<int PASS>
__global__ void pass_kernel(const float* __restrict__ u,
                            const float* __restrict__ W,
                            const float* __restrict__ vA,
                            const float* __restrict__ vB,
                            float* __restrict__ partial)
{
    const int tid   = threadIdx.x;
    const int bl    = tid >> 2;
    const int isub  = tid & 3;
    const int chunk = blockIdx.x >> 1;
    const int bg    = blockIdx.x & 1;
    const int b     = bg * 64 + bl;
    const int d0    = isub * 4;

    float v1q[NOUT][4];
    float v2q[NOUT][4];
    if constexpr (PASS >= 2) {
        #pragma unroll
        for (int o = 0; o < NOUT; ++o) {
            const float4 t = *reinterpret_cast<const float4*>(
                vA + ((size_t)b * NOUT + o) * DOUT + d0);
            v1q[o][0] = t.x; v1q[o][1] = t.y; v1q[o][2] = t.z; v1q[o][3] = t.w;
        }
    }
    if constexpr (PASS == 3) {
        #pragma unroll
        for (int o = 0; o < NOUT; ++o) {
            const float4 t = *reinterpret_cast<const float4*>(
                vB + ((size_t)b * NOUT + o) * DOUT + d0);
            v2q[o][0] = t.x; v2q[o][1] = t.y; v2q[o][2] = t.z; v2q[o][3] = t.w;
        }
    }

    float acc[NOUT][4];
    #pragma unroll
    for (int o = 0; o < NOUT; ++o)
        #pragma unroll
        for (int dd = 0; dd < 4; ++dd)
            acc[o][dd] = 0.0f;

    for (int ii = 0; ii < IBLK; ++ii) {
        const int i = chunk * IBLK + ii;

        const float* up = u + ((size_t)b * NIN + i) * DIN;
        const float4 ua = *reinterpret_cast<const float4*>(up);
        const float4 ub = *reinterpret_cast<const float4*>(up + 4);
        float ur[8] = {ua.x, ua.y, ua.z, ua.w, ub.x, ub.y, ub.z, ub.w};

        // u_hat for this thread's d-quarter, all o: 40 values, kept in regs
        float uh[NOUT][4];
        const float* wp = W + (size_t)i * NOUT * DOUT * DIN;
        #pragma unroll
        for (int o = 0; o < NOUT; ++o) {
            const float* wpo = wp + (size_t)o * DOUT * DIN + (size_t)d0 * DIN;
            #pragma unroll
            for (int dd = 0; dd < 4; ++dd) {
                const float4 wa = *reinterpret_cast<const float4*>(wpo + dd * DIN);
                const float4 wb = *reinterpret_cast<const float4*>(wpo + dd * DIN + 4);
                float t = wa.x * ur[0] + wa.y * ur[1] + wa.z * ur[2] + wa.w * ur[3]
                        + wb.x * ur[4] + wb.y * ur[5] + wb.z * ur[6] + wb.w * ur[7];
                uh[o][dd] = clip10(t);
            }
        }

        float c[NOUT];
        if constexpr (PASS == 1) {
            #pragma unroll
            for (int o = 0; o < NOUT; ++o) c[o] = 0.1f;
        } else {
            float lg[NOUT];
            #pragma unroll
            for (int o = 0; o < NOUT; ++o) {
                float a1 = uh[o][0] * v1q[o][0] + uh[o][1] * v1q[o][1]
                         + uh[o][2] * v1q[o][2] + uh[o][3] * v1q[o][3];
                a1 += __shfl_xor(a1, 1);
                a1 += __shfl_xor(a1, 2);
                float l = clip10(a1);
                if constexpr (PASS == 3) {
                    float a2 = uh[o][0] * v2q[o][0] + uh[o][1] * v2q[o][1]
                             + uh[o][2] * v2q[o][2] + uh[o][3] * v2q[o][3];
                    a2 += __shfl_xor(a2, 1);
                    a2 += __shfl_xor(a2, 2);
                    l += clip10(a2);
                }
                lg[o] = l;
            }
            float m = lg[0];
            #pragma unroll
            for (int o = 1; o < NOUT; ++o) m = fmaxf(m, lg[o]);
            float ssum = 0.0f;
            #pragma unroll
            for (int o = 0; o < NOUT; ++o) {
                const float e = __expf(lg[o] - m);
                c[o] = e;
                ssum += e;
            }
            const float inv = 1.0f / ssum;
            #pragma unroll
            for (int o = 0; o < NOUT; ++o) c[o] *= inv;
        }

        #pragma unroll
        for (int o = 0; o < NOUT; ++o)
            #pragma unroll
            for (int dd = 0; dd < 4; ++dd)
                acc[o][dd] += c[o] * uh[o][dd];
    }

    float* pp = partial + ((size_t)chunk * NB + b) * OD + d0;
    #pragma unroll
    for (int o = 0; o < NOUT; ++o) {
        *reinterpret_cast<float4*>(pp + o * DOUT) =
            make_float4(acc[o][0], acc[o][1], acc[o][2], acc[o][3]);
    }
}

// Reduce partials over chunks, then squash over d (16 lanes per (b,o)).
__global__ void squash_kernel(const float* __restrict__ partial,
                              float* __restrict__ vout)
{
    const int idx = blockIdx.x * 256 + threadIdx.x;   // 0..20479 = b*160 + o*16 + d
    float s = 0.0f;
    #pragma unroll 4
    for (int ch = 0; ch < NCHUNK; ++ch)
        s += partial[(size_t)ch * (NB * OD) + idx];

    float sq = s * s;
    sq += __shfl_xor(sq, 1);
    sq += __shfl_xor(sq, 2);
    sq += __shfl_xor(sq, 4);
    sq += __shfl_xor(sq, 8);
    sq = fminf(1e4f, fmaxf(1e-8f, sq));
    const float norm  = sqrtf(sq);
    const float scale = sq / (1.0f + sq);
    vout[idx] = scale * s / (norm + 1e-8f);
}

extern "C" void kernel_launch(void* const* d_in, const int* in_sizes, int n_in,
                              void* d_out, int out_size, void* d_ws, size_t ws_size,
                              hipStream_t stream)
{
    const float* u = (const float*)d_in[0];   // [128,1152,8]
    const float* W = (const float*)d_in[1];   // [1152,10,16,8]
    float* out = (float*)d_out;               // [128,10,16]

    float* partial = (float*)d_ws;                          // NCHUNK*NB*OD floats
    float* vA = partial + (size_t)NCHUNK * NB * OD;         // 20480 floats
    float* vB = vA + NB * OD;                               // 20480 floats

    const dim3 pg(NCHUNK * 2), pb(256);
    const dim3 sg(NB * OD / 256), sb(256);

    pass_kernel<1><<<pg, pb, 0, stream>>>(u, W, nullptr, nullptr, partial);
    squash_kernel<<<sg, sb, 0, stream>>>(partial, vA);
    pass_kernel<2><<<pg, pb, 0, stream>>>(u, W, vA, nullptr, partial);
    squash_kernel<<<sg, sb, 0, stream>>>(partial, vB);
    pass_kernel<3><<<pg, pb, 0, stream>>>(u, W, vA, vB, partial);
    squash_kernel<<<sg, sb, 0, stream>>>(partial, out);
}

// Round 2
// 244.917 us; speedup vs baseline: 3.6389x; 3.6389x over previous
//
#include <hip/hip_runtime.h>
#include <cstddef>

#define NB     128
#define NIN    1152
#define NOUT   10
#define DOUT   16
#define DIN    8
#define IBLK   8
#define NCHUNK (NIN / IBLK)      // 144
#define OD     (NOUT * DOUT)     // 160

__device__ __forceinline__ float clip10(float x) {
    return fminf(10.0f, fmaxf(-10.0f, x));
}

// 256 threads: tid = bl*8 + isub
//   bl   = tid >> 3 (0..31) -> b = bg*32 + bl
//   isub = tid & 7          -> owns d in [isub*2, isub*2+2) for every o
// grid = NCHUNK*4 : chunk = bx>>2, bg = bx&3
template<int PASS>
__global__ __launch_bounds__(256)
void pass_kernel(const float* __restrict__ u,
                 const float* __restrict__ W,
                 const float* __restrict__ vA,
                 const float* __restrict__ vB,
                 float* __restrict__ partial)
{
    const int tid   = threadIdx.x;
    const int bl    = tid >> 3;
    const int isub  = tid & 7;
    const int chunk = blockIdx.x >> 2;
    const int bg    = blockIdx.x & 3;
    const int b     = bg * 32 + bl;
    const int d0    = isub * 2;

    float v1q[NOUT][2];
    float v2q[NOUT][2];
    if constexpr (PASS >= 2) {
        #pragma unroll
        for (int o = 0; o < NOUT; ++o) {
            const float2 t = *reinterpret_cast<const float2*>(
                vA + ((size_t)b * NOUT + o) * DOUT + d0);
            v1q[o][0] = t.x; v1q[o][1] = t.y;
        }
    }
    if constexpr (PASS == 3) {
        #pragma unroll
        for (int o = 0; o < NOUT; ++o) {
            const float2 t = *reinterpret_cast<const float2*>(
                vB + ((size_t)b * NOUT + o) * DOUT + d0);
            v2q[o][0] = t.x; v2q[o][1] = t.y;
        }
    }

    float acc[NOUT][2];
    #pragma unroll
    for (int o = 0; o < NOUT; ++o) {
        acc[o][0] = 0.0f; acc[o][1] = 0.0f;
    }

    for (int ii = 0; ii < IBLK; ++ii) {
        const int i = chunk * IBLK + ii;

        const float* up = u + ((size_t)b * NIN + i) * DIN;
        const float4 ua = *reinterpret_cast<const float4*>(up);
        const float4 ub = *reinterpret_cast<const float4*>(up + 4);
        float ur[8] = {ua.x, ua.y, ua.z, ua.w, ub.x, ub.y, ub.z, ub.w};

        // u_hat for this thread's d-pair, all o: 20 values, kept in regs
        float uh[NOUT][2];
        const float* wp = W + (size_t)i * NOUT * DOUT * DIN;
        #pragma unroll
        for (int o = 0; o < NOUT; ++o) {
            const float* wpo = wp + (size_t)o * DOUT * DIN + (size_t)d0 * DIN;
            #pragma unroll
            for (int dd = 0; dd < 2; ++dd) {
                const float4 wa = *reinterpret_cast<const float4*>(wpo + dd * DIN);
                const float4 wb = *reinterpret_cast<const float4*>(wpo + dd * DIN + 4);
                float t = wa.x * ur[0] + wa.y * ur[1] + wa.z * ur[2] + wa.w * ur[3]
                        + wb.x * ur[4] + wb.y * ur[5] + wb.z * ur[6] + wb.w * ur[7];
                uh[o][dd] = clip10(t);
            }
        }

        float c[NOUT];
        if constexpr (PASS == 1) {
            #pragma unroll
            for (int o = 0; o < NOUT; ++o) c[o] = 0.1f;
        } else {
            float lg[NOUT];
            #pragma unroll
            for (int o = 0; o < NOUT; ++o) {
                float a1 = uh[o][0] * v1q[o][0] + uh[o][1] * v1q[o][1];
                a1 += __shfl_xor(a1, 1);
                a1 += __shfl_xor(a1, 2);
                a1 += __shfl_xor(a1, 4);
                float l = clip10(a1);
                if constexpr (PASS == 3) {
                    float a2 = uh[o][0] * v2q[o][0] + uh[o][1] * v2q[o][1];
                    a2 += __shfl_xor(a2, 1);
                    a2 += __shfl_xor(a2, 2);
                    a2 += __shfl_xor(a2, 4);
                    l += clip10(a2);
                }
                lg[o] = l;
            }
            float m = lg[0];
            #pragma unroll
            for (int o = 1; o < NOUT; ++o) m = fmaxf(m, lg[o]);
            float ssum = 0.0f;
            #pragma unroll
            for (int o = 0; o < NOUT; ++o) {
                const float e = __expf(lg[o] - m);
                c[o] = e;
                ssum += e;
            }
            const float inv = 1.0f / ssum;
            #pragma unroll
            for (int o = 0; o < NOUT; ++o) c[o] *= inv;
        }

        #pragma unroll
        for (int o = 0; o < NOUT; ++o) {
            acc[o][0] += c[o] * uh[o][0];
            acc[o][1] += c[o] * uh[o][1];
        }
    }

    float* pp = partial + ((size_t)chunk * NB + b) * OD + d0;
    #pragma unroll
    for (int o = 0; o < NOUT; ++o) {
        *reinterpret_cast<float2*>(pp + o * DOUT) =
            make_float2(acc[o][0], acc[o][1]);
    }
}

// Reduce partials over chunks, then squash over d (16 lanes per (b,o)).
__global__ __launch_bounds__(256)
void squash_kernel(const float* __restrict__ partial,
                   float* __restrict__ vout)
{
    const int idx = blockIdx.x * 256 + threadIdx.x;   // 0..20479 = b*160 + o*16 + d
    float s = 0.0f;
    #pragma unroll 4
    for (int ch = 0; ch < NCHUNK; ++ch)
        s += partial[(size_t)ch * (NB * OD) + idx];

    float sq = s * s;
    sq += __shfl_xor(sq, 1);
    sq += __shfl_xor(sq, 2);
    sq += __shfl_xor(sq, 4);
    sq += __shfl_xor(sq, 8);
    sq = fminf(1e4f, fmaxf(1e-8f, sq));
    const float norm  = sqrtf(sq);
    const float scale = sq / (1.0f + sq);
    vout[idx] = scale * s / (norm + 1e-8f);
}

extern "C" void kernel_launch(void* const* d_in, const int* in_sizes, int n_in,
                              void* d_out, int out_size, void* d_ws, size_t ws_size,
                              hipStream_t stream)
{
    const float* u = (const float*)d_in[0];   // [128,1152,8]
    const float* W = (const float*)d_in[1];   // [1152,10,16,8]
    float* out = (float*)d_out;               // [128,10,16]

    float* partial = (float*)d_ws;                          // NCHUNK*NB*OD floats
    float* vA = partial + (size_t)NCHUNK * NB * OD;         // 20480 floats
    float* vB = vA + NB * OD;                               // 20480 floats

    const dim3 pg(NCHUNK * 4), pb(256);
    const dim3 sg(NB * OD / 256), sb(256);

    pass_kernel<1><<<pg, pb, 0, stream>>>(u, W, nullptr, nullptr, partial);
    squash_kernel<<<sg, sb, 0, stream>>>(partial, vA);
    pass_kernel<2><<<pg, pb, 0, stream>>>(u, W, vA, nullptr, partial);
    squash_kernel<<<sg, sb, 0, stream>>>(partial, vB);
    pass_kernel<3><<<pg, pb, 0, stream>>>(u, W, vA, vB, partial);
    squash_kernel<<<sg, sb, 0, stream>>>(partial, out);
}

// Round 3
// 173.365 us; speedup vs baseline: 5.1408x; 1.4127x over previous
//
#include <hip/hip_runtime.h>
#include <cstddef>

#define NB     128
#define NIN    1152
#define NOUT   10
#define DOUT   16
#define DIN    8
#define OD     (NOUT * DOUT)     // 160

__device__ __forceinline__ float clip10(float x) {
    return fminf(10.0f, fmaxf(-10.0f, x));
}

// 256 threads: tid = bl*16 + isub
//   bl   = tid >> 4 (0..15) -> b = bg*16 + bl
//   isub = tid & 15         -> owns d = isub for every o
// grid = NCHUNK*8 : chunk = bx>>3, bg = bx&7
template<int PASS, int IBLK>
__global__ __launch_bounds__(256)
void pass_kernel(const float* __restrict__ u,
                 const float* __restrict__ W,
                 const float* __restrict__ vA,
                 const float* __restrict__ vB,
                 float* __restrict__ partial)
{
    const int tid   = threadIdx.x;
    const int bl    = tid >> 4;
    const int d     = tid & 15;
    const int chunk = blockIdx.x >> 3;
    const int bg    = blockIdx.x & 7;
    const int b     = bg * 16 + bl;

    float v1q[NOUT];
    float v2q[NOUT];
    if constexpr (PASS >= 2) {
        #pragma unroll
        for (int o = 0; o < NOUT; ++o)
            v1q[o] = vA[((size_t)b * NOUT + o) * DOUT + d];
    }
    if constexpr (PASS == 3) {
        #pragma unroll
        for (int o = 0; o < NOUT; ++o)
            v2q[o] = vB[((size_t)b * NOUT + o) * DOUT + d];
    }

    float acc[NOUT];
    #pragma unroll
    for (int o = 0; o < NOUT; ++o) acc[o] = 0.0f;

    for (int ii = 0; ii < IBLK; ++ii) {
        const int i = chunk * IBLK + ii;

        const float* up = u + ((size_t)b * NIN + i) * DIN;
        const float4 ua = *reinterpret_cast<const float4*>(up);
        const float4 ub = *reinterpret_cast<const float4*>(up + 4);

        // u_hat for this thread's single d, all o: 10 values in regs
        float uh[NOUT];
        const float* wp = W + ((size_t)i * NOUT * DOUT + d) * DIN;
        #pragma unroll
        for (int o = 0; o < NOUT; ++o) {
            const float* wpo = wp + (size_t)o * DOUT * DIN;
            const float4 wa = *reinterpret_cast<const float4*>(wpo);
            const float4 wb = *reinterpret_cast<const float4*>(wpo + 4);
            float t = wa.x * ua.x + wa.y * ua.y + wa.z * ua.z + wa.w * ua.w
                    + wb.x * ub.x + wb.y * ub.y + wb.z * ub.z + wb.w * ub.w;
            uh[o] = clip10(t);
        }

        float c[NOUT];
        if constexpr (PASS == 1) {
            #pragma unroll
            for (int o = 0; o < NOUT; ++o) c[o] = 0.1f;
        } else {
            float lg[NOUT];
            #pragma unroll
            for (int o = 0; o < NOUT; ++o) {
                float a1 = uh[o] * v1q[o];
                a1 += __shfl_xor(a1, 1);
                a1 += __shfl_xor(a1, 2);
                a1 += __shfl_xor(a1, 4);
                a1 += __shfl_xor(a1, 8);
                float l = clip10(a1);
                if constexpr (PASS == 3) {
                    float a2 = uh[o] * v2q[o];
                    a2 += __shfl_xor(a2, 1);
                    a2 += __shfl_xor(a2, 2);
                    a2 += __shfl_xor(a2, 4);
                    a2 += __shfl_xor(a2, 8);
                    l += clip10(a2);
                }
                lg[o] = l;
            }
            float m = lg[0];
            #pragma unroll
            for (int o = 1; o < NOUT; ++o) m = fmaxf(m, lg[o]);
            float ssum = 0.0f;
            #pragma unroll
            for (int o = 0; o < NOUT; ++o) {
                const float e = __expf(lg[o] - m);
                c[o] = e;
                ssum += e;
            }
            const float inv = 1.0f / ssum;
            #pragma unroll
            for (int o = 0; o < NOUT; ++o) c[o] *= inv;
        }

        #pragma unroll
        for (int o = 0; o < NOUT; ++o)
            acc[o] += c[o] * uh[o];
    }

    float* pp = partial + ((size_t)chunk * NB + b) * OD + d;
    #pragma unroll
    for (int o = 0; o < NOUT; ++o)
        pp[o * DOUT] = acc[o];
}

// Reduce partials over chunks, then squash over d (16 lanes per (b,o)).
template<int NCHUNK>
__global__ __launch_bounds__(256)
void squash_kernel(const float* __restrict__ partial,
                   float* __restrict__ vout)
{
    const int idx = blockIdx.x * 256 + threadIdx.x;   // 0..20479 = b*160 + o*16 + d
    float s = 0.0f;
    #pragma unroll 4
    for (int ch = 0; ch < NCHUNK; ++ch)
        s += partial[(size_t)ch * (NB * OD) + idx];

    float sq = s * s;
    sq += __shfl_xor(sq, 1);
    sq += __shfl_xor(sq, 2);
    sq += __shfl_xor(sq, 4);
    sq += __shfl_xor(sq, 8);
    sq = fminf(1e4f, fmaxf(1e-8f, sq));
    const float norm  = sqrtf(sq);
    const float scale = sq / (1.0f + sq);
    vout[idx] = scale * s / (norm + 1e-8f);
}

template<int IBLK>
static void run_all(const float* u, const float* W, float* out,
                    void* d_ws, hipStream_t stream)
{
    constexpr int NCHUNK = NIN / IBLK;
    float* partial = (float*)d_ws;                          // NCHUNK*NB*OD floats
    float* vA = partial + (size_t)NCHUNK * NB * OD;         // 20480 floats
    float* vB = vA + NB * OD;                               // 20480 floats

    const dim3 pg(NCHUNK * 8), pb(256);
    const dim3 sg(NB * OD / 256), sb(256);

    pass_kernel<1, IBLK><<<pg, pb, 0, stream>>>(u, W, nullptr, nullptr, partial);
    squash_kernel<NCHUNK><<<sg, sb, 0, stream>>>(partial, vA);
    pass_kernel<2, IBLK><<<pg, pb, 0, stream>>>(u, W, vA, nullptr, partial);
    squash_kernel<NCHUNK><<<sg, sb, 0, stream>>>(partial, vB);
    pass_kernel<3, IBLK><<<pg, pb, 0, stream>>>(u, W, vA, vB, partial);
    squash_kernel<NCHUNK><<<sg, sb, 0, stream>>>(partial, out);
}

extern "C" void kernel_launch(void* const* d_in, const int* in_sizes, int n_in,
                              void* d_out, int out_size, void* d_ws, size_t ws_size,
                              hipStream_t stream)
{
    const float* u = (const float*)d_in[0];   // [128,1152,8]
    const float* W = (const float*)d_in[1];   // [1152,10,16,8]
    float* out = (float*)d_out;               // [128,10,16]

    const size_t need4 = ((size_t)(NIN / 4) * NB * OD + 2 * NB * OD) * sizeof(float);
    if (ws_size >= need4)
        run_all<4>(u, W, out, d_ws, stream);
    else
        run_all<8>(u, W, out, d_ws, stream);
}

// Round 4
// 128.719 us; speedup vs baseline: 6.9239x; 1.3468x over previous
//
#include <hip/hip_runtime.h>
#include <cstddef>

#define NB    128
#define NIN   1152
#define NOUT  10
#define DOUT  16
#define DIN   8
#define OD    (NOUT * DOUT)   // 160
#define CH    288             // partial chunks (i-groups of 4)
#define NI    4               // i's per wave
#define CGRP  72              // chunk groups; pass grid = 8*CGRP = 576 blocks

typedef __attribute__((ext_vector_type(8))) short          bf16x8;
typedef __attribute__((ext_vector_type(4))) float          f32x4;
typedef __attribute__((ext_vector_type(8))) unsigned short u16x8;
typedef __attribute__((ext_vector_type(4))) unsigned short u16x4;

__device__ __forceinline__ unsigned short f2bf(float x) {
    union { float f; unsigned u; } v; v.f = x;
    const unsigned r = v.u + 0x7fffu + ((v.u >> 16) & 1u);  // RNE
    return (unsigned short)(r >> 16);
}
__device__ __forceinline__ float bf2f(unsigned short h) {
    union { unsigned u; float f; } v; v.u = ((unsigned)h) << 16;
    return v.f;
}
__device__ __forceinline__ float clip10(float x) {
    return fminf(10.0f, fmaxf(-10.0f, x));
}
__device__ __forceinline__ f32x4 clip4(f32x4 r) {
    #pragma unroll
    for (int q = 0; q < 4; ++q) r[q] = clip10(r[q]);
    return r;
}

// Convert W -> bf16 [i][o][d][k]; u -> bf16 transposed [i][b][k].
__global__ __launch_bounds__(256)
void prep_kernel(const float* __restrict__ u, const float* __restrict__ W,
                 unsigned short* __restrict__ Wb, unsigned short* __restrict__ ubT)
{
    const int t = blockIdx.x * 256 + threadIdx.x;
    if (blockIdx.x < 720) {
        // 184320 threads x 8 elems = 1,474,560 = NIN*NOUT*DOUT*DIN
        const float4 a = *reinterpret_cast<const float4*>(W + (size_t)t * 8);
        const float4 c = *reinterpret_cast<const float4*>(W + (size_t)t * 8 + 4);
        u16x8 o;
        o[0] = f2bf(a.x); o[1] = f2bf(a.y); o[2] = f2bf(a.z); o[3] = f2bf(a.w);
        o[4] = f2bf(c.x); o[5] = f2bf(c.y); o[6] = f2bf(c.z); o[7] = f2bf(c.w);
        *reinterpret_cast<u16x8*>(Wb + (size_t)t * 8) = o;
    } else {
        const int t2 = t - 720 * 256;          // 0..147455 = b*NIN + i
        const int b  = t2 / NIN;
        const int i  = t2 - b * NIN;
        const float4 a = *reinterpret_cast<const float4*>(u + (size_t)t2 * 8);
        const float4 c = *reinterpret_cast<const float4*>(u + (size_t)t2 * 8 + 4);
        u16x8 o;
        o[0] = f2bf(a.x); o[1] = f2bf(a.y); o[2] = f2bf(a.z); o[3] = f2bf(a.w);
        o[4] = f2bf(c.x); o[5] = f2bf(c.y); o[6] = f2bf(c.z); o[7] = f2bf(c.w);
        *reinterpret_cast<u16x8*>(ubT + ((size_t)i * NB + b) * 8) = o;
    }
}

// Wave layout: lane = rg*16 + b16.  b = bt*16 + b16, d = rg*4 + j (mfma C layout).
// Wave handles (chunk = cg*4 + wid, bt); NI i's per wave; one mfma per (i,o):
//   D[d][b] = sum_k W[i][o][d][k] * u[b][i][k]   (K=8, lanes>=16 B-frag zeroed)
template<int PASS>
__global__ __launch_bounds__(256)
void pass_kernel(const unsigned short* __restrict__ Wb,
                 const unsigned short* __restrict__ ubT,
                 const float* __restrict__ vA, const float* __restrict__ vB,
                 unsigned short* __restrict__ partial)
{
    const int tid   = threadIdx.x;
    const int wid   = tid >> 6;
    const int lane  = tid & 63;
    const int b16   = lane & 15;
    const int rg    = lane >> 4;
    const int bt    = blockIdx.x & 7;
    const int cg    = blockIdx.x >> 3;
    const int chunk = cg * 4 + wid;          // 0..287
    const int b     = bt * 16 + b16;
    const int d0    = rg * 4;

    float v1[NOUT][4];
    float v2[NOUT][4];
    if constexpr (PASS >= 2) {
        #pragma unroll
        for (int o = 0; o < NOUT; ++o) {
            const float4 t = *reinterpret_cast<const float4*>(
                vA + ((size_t)b * NOUT + o) * DOUT + d0);
            v1[o][0] = t.x; v1[o][1] = t.y; v1[o][2] = t.z; v1[o][3] = t.w;
        }
    }
    if constexpr (PASS == 3) {
        #pragma unroll
        for (int o = 0; o < NOUT; ++o) {
            const float4 t = *reinterpret_cast<const float4*>(
                vB + ((size_t)b * NOUT + o) * DOUT + d0);
            v2[o][0] = t.x; v2[o][1] = t.y; v2[o][2] = t.z; v2[o][3] = t.w;
        }
    }

    f32x4 acc[NOUT];
    #pragma unroll
    for (int o = 0; o < NOUT; ++o) acc[o] = (f32x4){0.0f, 0.0f, 0.0f, 0.0f};

    for (int ii = 0; ii < NI; ++ii) {
        const int i = chunk * NI + ii;

        // B fragment: u[b][i][k] for k=0..7 on lanes 0-15; zero for lanes>=16
        bf16x8 bfrag = *reinterpret_cast<const bf16x8*>(
            ubT + ((size_t)i * NB + bt * 16 + b16) * 8);
        if (lane >= 16) {
            #pragma unroll
            for (int q = 0; q < 8; ++q) bfrag[q] = 0;
        }

        f32x4 uh[NOUT];
        #pragma unroll
        for (int o = 0; o < NOUT; ++o) {
            // A fragment: W[i][o][d=b16][k] (lanes>=16 hold duplicates; their
            // products hit the zeroed B rows, contributing exactly 0)
            const bf16x8 afrag = *reinterpret_cast<const bf16x8*>(
                Wb + (((size_t)i * NOUT + o) * DOUT + b16) * 8);
            const f32x4 z = (f32x4){0.0f, 0.0f, 0.0f, 0.0f};
            f32x4 r = __builtin_amdgcn_mfma_f32_16x16x32_bf16(afrag, bfrag, z, 0, 0, 0);
            uh[o] = clip4(r);
        }

        float c[NOUT];
        if constexpr (PASS == 1) {
            #pragma unroll
            for (int o = 0; o < NOUT; ++o) c[o] = 0.1f;
        } else {
            float lg[NOUT];
            #pragma unroll
            for (int o = 0; o < NOUT; ++o) {
                float a1 = uh[o][0] * v1[o][0] + uh[o][1] * v1[o][1]
                         + uh[o][2] * v1[o][2] + uh[o][3] * v1[o][3];
                a1 += __shfl_xor(a1, 16);
                a1 += __shfl_xor(a1, 32);
                float l = clip10(a1);
                if constexpr (PASS == 3) {
                    float a2 = uh[o][0] * v2[o][0] + uh[o][1] * v2[o][1]
                             + uh[o][2] * v2[o][2] + uh[o][3] * v2[o][3];
                    a2 += __shfl_xor(a2, 16);
                    a2 += __shfl_xor(a2, 32);
                    l += clip10(a2);
                }
                lg[o] = l;
            }
            float m = lg[0];
            #pragma unroll
            for (int o = 1; o < NOUT; ++o) m = fmaxf(m, lg[o]);
            float ssum = 0.0f;
            #pragma unroll
            for (int o = 0; o < NOUT; ++o) {
                const float e = __expf(lg[o] - m);
                c[o] = e;
                ssum += e;
            }
            const float inv = 1.0f / ssum;
            #pragma unroll
            for (int o = 0; o < NOUT; ++o) c[o] *= inv;
        }

        #pragma unroll
        for (int o = 0; o < NOUT; ++o)
            acc[o] += uh[o] * c[o];
    }

    unsigned short* pp = partial + ((size_t)chunk * NB + b) * OD + d0;
    #pragma unroll
    for (int o = 0; o < NOUT; ++o) {
        u16x4 st;
        st[0] = f2bf(acc[o][0]); st[1] = f2bf(acc[o][1]);
        st[2] = f2bf(acc[o][2]); st[3] = f2bf(acc[o][3]);
        *reinterpret_cast<u16x4*>(pp + o * DOUT) = st;
    }
}

// Reduce bf16 partials over CH chunks, then squash over d (16 lanes per (b,o)).
__global__ __launch_bounds__(256)
void squash_kernel(const unsigned short* __restrict__ partial,
                   float* __restrict__ vout)
{
    const int idx = blockIdx.x * 256 + threadIdx.x;   // b*160 + o*16 + d
    float s = 0.0f;
    #pragma unroll 8
    for (int ch = 0; ch < CH; ++ch)
        s += bf2f(partial[(size_t)ch * (NB * OD) + idx]);

    float sq = s * s;
    sq += __shfl_xor(sq, 1);
    sq += __shfl_xor(sq, 2);
    sq += __shfl_xor(sq, 4);
    sq += __shfl_xor(sq, 8);
    sq = fminf(1e4f, fmaxf(1e-8f, sq));
    const float norm  = sqrtf(sq);
    const float scale = sq / (1.0f + sq);
    vout[idx] = scale * s / (norm + 1e-8f);
}

extern "C" void kernel_launch(void* const* d_in, const int* in_sizes, int n_in,
                              void* d_out, int out_size, void* d_ws, size_t ws_size,
                              hipStream_t stream)
{
    const float* u = (const float*)d_in[0];   // [128,1152,8]
    const float* W = (const float*)d_in[1];   // [1152,10,16,8]
    float* out = (float*)d_out;               // [128,10,16]

    // ws carve (bytes): partial bf16 11.8MB | vA 80KB | vB 80KB | Wb 2.95MB | ubT 2.36MB
    unsigned short* partial = (unsigned short*)d_ws;
    float* vAp = (float*)((char*)d_ws + (size_t)CH * NB * OD * 2);
    float* vBp = vAp + NB * OD;
    unsigned short* Wb  = (unsigned short*)(vBp + NB * OD);
    unsigned short* ubT = Wb + (size_t)NIN * NOUT * DOUT * DIN;

    const dim3 pg(CGRP * 8), pb(256);
    const dim3 sg(NB * OD / 256), sb(256);

    prep_kernel<<<dim3(1296), pb, 0, stream>>>(u, W, Wb, ubT);
    pass_kernel<1><<<pg, pb, 0, stream>>>(Wb, ubT, nullptr, nullptr, partial);
    squash_kernel<<<sg, sb, 0, stream>>>(partial, vAp);
    pass_kernel<2><<<pg, pb, 0, stream>>>(Wb, ubT, vAp, nullptr, partial);
    squash_kernel<<<sg, sb, 0, stream>>>(partial, vBp);
    pass_kernel<3><<<pg, pb, 0, stream>>>(Wb, ubT, vAp, vBp, partial);
    squash_kernel<<<sg, sb, 0, stream>>>(partial, out);
}

// Round 5
// 113.840 us; speedup vs baseline: 7.8289x; 1.1307x over previous
//
#include <hip/hip_runtime.h>
#include <cstddef>

#define NB    128
#define NIN   1152
#define NOUT  10
#define DOUT  16
#define DIN   8
#define OD    (NOUT * DOUT)   // 160
#define CH    288             // partial chunks (i-groups of 4, one block each)

typedef __attribute__((ext_vector_type(8))) short          bf16x8;
typedef __attribute__((ext_vector_type(4))) float          f32x4;
typedef __attribute__((ext_vector_type(8))) unsigned short u16x8;
typedef __attribute__((ext_vector_type(4))) unsigned short u16x4;

__device__ __forceinline__ unsigned short f2bf(float x) {
    union { float f; unsigned u; } v; v.f = x;
    const unsigned r = v.u + 0x7fffu + ((v.u >> 16) & 1u);  // RNE
    return (unsigned short)(r >> 16);
}
__device__ __forceinline__ float bf2f(unsigned short h) {
    union { unsigned u; float f; } v; v.u = ((unsigned)h) << 16;
    return v.f;
}
__device__ __forceinline__ float clip10(float x) {
    return fminf(10.0f, fmaxf(-10.0f, x));
}
__device__ __forceinline__ f32x4 clip4(f32x4 r) {
    #pragma unroll
    for (int q = 0; q < 4; ++q) r[q] = clip10(r[q]);
    return r;
}

// Convert W -> bf16 [i][o][d][k]; u -> bf16 transposed [i][b][k].
__global__ __launch_bounds__(256)
void prep_kernel(const float* __restrict__ u, const float* __restrict__ W,
                 unsigned short* __restrict__ Wb, unsigned short* __restrict__ ubT)
{
    const int t = blockIdx.x * 256 + threadIdx.x;
    if (blockIdx.x < 720) {
        const float4 a = *reinterpret_cast<const float4*>(W + (size_t)t * 8);
        const float4 c = *reinterpret_cast<const float4*>(W + (size_t)t * 8 + 4);
        u16x8 o;
        o[0] = f2bf(a.x); o[1] = f2bf(a.y); o[2] = f2bf(a.z); o[3] = f2bf(a.w);
        o[4] = f2bf(c.x); o[5] = f2bf(c.y); o[6] = f2bf(c.z); o[7] = f2bf(c.w);
        *reinterpret_cast<u16x8*>(Wb + (size_t)t * 8) = o;
    } else {
        const int t2 = t - 720 * 256;          // 0..147455 = b*NIN + i
        const int b  = t2 / NIN;
        const int i  = t2 - b * NIN;
        const float4 a = *reinterpret_cast<const float4*>(u + (size_t)t2 * 8);
        const float4 c = *reinterpret_cast<const float4*>(u + (size_t)t2 * 8 + 4);
        u16x8 o;
        o[0] = f2bf(a.x); o[1] = f2bf(a.y); o[2] = f2bf(a.z); o[3] = f2bf(a.w);
        o[4] = f2bf(c.x); o[5] = f2bf(c.y); o[6] = f2bf(c.z); o[7] = f2bf(c.w);
        *reinterpret_cast<u16x8*>(ubT + ((size_t)i * NB + b) * 8) = o;
    }
}

// One i per wave; 4 waves of a block cover i = ig*4 + wid and LDS-reduce.
// Wave layout: lane = rg*16 + b16; b = bt*16 + b16; d = rg*4 + j (mfma C map).
// grid = CH*8: ig = bx>>3, bt = bx&7.
template<int PASS>
__global__ __launch_bounds__(256)
void pass_kernel(const unsigned short* __restrict__ Wb,
                 const unsigned short* __restrict__ ubT,
                 const float* __restrict__ vA, const float* __restrict__ vB,
                 unsigned short* __restrict__ partial)
{
    __shared__ float red[3][64][41];   // 41-pad: lane stride 41w -> conflict-free

    const int tid  = threadIdx.x;
    const int wid  = tid >> 6;
    const int lane = tid & 63;
    const int b16  = lane & 15;
    const int rg   = lane >> 4;
    const int ig   = blockIdx.x >> 3;
    const int bt   = blockIdx.x & 7;
    const int i    = ig * 4 + wid;
    const int b    = bt * 16 + b16;
    const int d0   = rg * 4;

    // B fragment: u[b][i][k], lanes >= 16 zeroed (k>=8 contributes 0)
    bf16x8 bfrag = *reinterpret_cast<const bf16x8*>(
        ubT + ((size_t)i * NB + b) * 8);
    if (lane >= 16) {
        #pragma unroll
        for (int q = 0; q < 8; ++q) bfrag[q] = 0;
    }

    f32x4 uh[NOUT];
    #pragma unroll
    for (int o = 0; o < NOUT; ++o) {
        const bf16x8 afrag = *reinterpret_cast<const bf16x8*>(
            Wb + (((size_t)i * NOUT + o) * DOUT + b16) * 8);
        const f32x4 z = (f32x4){0.0f, 0.0f, 0.0f, 0.0f};
        uh[o] = clip4(__builtin_amdgcn_mfma_f32_16x16x32_bf16(afrag, bfrag, z, 0, 0, 0));
    }

    float c[NOUT];
    if constexpr (PASS == 1) {
        #pragma unroll
        for (int o = 0; o < NOUT; ++o) c[o] = 0.1f;
    } else {
        float lg[NOUT];
        #pragma unroll
        for (int o = 0; o < NOUT; ++o) {
            const float4 t = *reinterpret_cast<const float4*>(
                vA + ((size_t)b * NOUT + o) * DOUT + d0);
            float a1 = uh[o][0] * t.x + uh[o][1] * t.y + uh[o][2] * t.z + uh[o][3] * t.w;
            a1 += __shfl_xor(a1, 16);
            a1 += __shfl_xor(a1, 32);
            lg[o] = clip10(a1);
        }
        if constexpr (PASS == 3) {
            #pragma unroll
            for (int o = 0; o < NOUT; ++o) {
                const float4 t = *reinterpret_cast<const float4*>(
                    vB + ((size_t)b * NOUT + o) * DOUT + d0);
                float a2 = uh[o][0] * t.x + uh[o][1] * t.y + uh[o][2] * t.z + uh[o][3] * t.w;
                a2 += __shfl_xor(a2, 16);
                a2 += __shfl_xor(a2, 32);
                lg[o] += clip10(a2);
            }
        }
        float m = lg[0];
        #pragma unroll
        for (int o = 1; o < NOUT; ++o) m = fmaxf(m, lg[o]);
        float ssum = 0.0f;
        #pragma unroll
        for (int o = 0; o < NOUT; ++o) {
            const float e = __expf(lg[o] - m);
            c[o] = e;
            ssum += e;
        }
        const float inv = 1.0f / ssum;
        #pragma unroll
        for (int o = 0; o < NOUT; ++o) c[o] *= inv;
    }

    #pragma unroll
    for (int o = 0; o < NOUT; ++o)
        uh[o] *= c[o];

    if (wid > 0) {
        #pragma unroll
        for (int o = 0; o < NOUT; ++o)
            #pragma unroll
            for (int q = 0; q < 4; ++q)
                red[wid - 1][lane][o * 4 + q] = uh[o][q];
    }
    __syncthreads();
    if (wid == 0) {
        #pragma unroll
        for (int w = 0; w < 3; ++w)
            #pragma unroll
            for (int o = 0; o < NOUT; ++o)
                #pragma unroll
                for (int q = 0; q < 4; ++q)
                    uh[o][q] += red[w][lane][o * 4 + q];

        unsigned short* pp = partial + ((size_t)ig * NB + b) * OD + d0;
        #pragma unroll
        for (int o = 0; o < NOUT; ++o) {
            u16x4 st;
            st[0] = f2bf(uh[o][0]); st[1] = f2bf(uh[o][1]);
            st[2] = f2bf(uh[o][2]); st[3] = f2bf(uh[o][3]);
            *reinterpret_cast<u16x4*>(pp + o * DOUT) = st;
        }
    }
}

// Reduce bf16 partials over CH chunks, then squash over d (16 lanes per (b,o)).
__global__ __launch_bounds__(256)
void squash_kernel(const unsigned short* __restrict__ partial,
                   float* __restrict__ vout)
{
    const int idx = blockIdx.x * 256 + threadIdx.x;   // b*160 + o*16 + d
    float s = 0.0f;
    #pragma unroll 8
    for (int ch = 0; ch < CH; ++ch)
        s += bf2f(partial[(size_t)ch * (NB * OD) + idx]);

    float sq = s * s;
    sq += __shfl_xor(sq, 1);
    sq += __shfl_xor(sq, 2);
    sq += __shfl_xor(sq, 4);
    sq += __shfl_xor(sq, 8);
    sq = fminf(1e4f, fmaxf(1e-8f, sq));
    const float norm  = sqrtf(sq);
    const float scale = sq / (1.0f + sq);
    vout[idx] = scale * s / (norm + 1e-8f);
}

extern "C" void kernel_launch(void* const* d_in, const int* in_sizes, int n_in,
                              void* d_out, int out_size, void* d_ws, size_t ws_size,
                              hipStream_t stream)
{
    const float* u = (const float*)d_in[0];   // [128,1152,8]
    const float* W = (const float*)d_in[1];   // [1152,10,16,8]
    float* out = (float*)d_out;               // [128,10,16]

    // ws carve: partial bf16 11.8MB | vA 80KB | vB 80KB | Wb 2.95MB | ubT 2.36MB
    unsigned short* partial = (unsigned short*)d_ws;
    float* vAp = (float*)((char*)d_ws + (size_t)CH * NB * OD * 2);
    float* vBp = vAp + NB * OD;
    unsigned short* Wb  = (unsigned short*)(vBp + NB * OD);
    unsigned short* ubT = Wb + (size_t)NIN * NOUT * DOUT * DIN;

    const dim3 pg(CH * 8), pb(256);
    const dim3 sg(NB * OD / 256), sb(256);

    prep_kernel<<<dim3(1296), pb, 0, stream>>>(u, W, Wb, ubT);
    pass_kernel<1><<<pg, pb, 0, stream>>>(Wb, ubT, nullptr, nullptr, partial);
    squash_kernel<<<sg, sb, 0, stream>>>(partial, vAp);
    pass_kernel<2><<<pg, pb, 0, stream>>>(Wb, ubT, vAp, nullptr, partial);
    squash_kernel<<<sg, sb, 0, stream>>>(partial, vBp);
    pass_kernel<3><<<pg, pb, 0, stream>>>(Wb, ubT, vAp, vBp, partial);
    squash_kernel<<<sg, sb, 0, stream>>>(partial, out);
}